// Round 1
// baseline (190.493 us; speedup 1.0000x reference)
//
#include <hip/hip_runtime.h>
#include <hip/hip_bf16.h>

#define BATCH   1000000
#define NTILES  15625   // BATCH / 64

typedef __attribute__((ext_vector_type(8))) short bf16x8;
typedef __attribute__((ext_vector_type(4))) float f32x4;

__device__ __forceinline__ unsigned short f2b_rne(float f) {
    unsigned u = __builtin_bit_cast(unsigned, f);
    u += 0x7FFFu + ((u >> 16) & 1u);
    return (unsigned short)(u >> 16);
}
__device__ __forceinline__ float b2f(unsigned short h) {
    unsigned u = ((unsigned)h) << 16;
    return __builtin_bit_cast(float, u);
}
__device__ __forceinline__ float tanh_fast(float x) {
    float e = __expf(2.0f * x);                       // v_mul + v_exp
    return 1.0f - 2.0f * __builtin_amdgcn_rcpf(e + 1.0f);
}

__global__ __launch_bounds__(256, 3)
void dgm_lstm_kernel(const float* __restrict__ S, const float* __restrict__ X,
                     const float* __restrict__ U0, const float* __restrict__ U1,
                     const float* __restrict__ U2, const float* __restrict__ U3,
                     const float* __restrict__ W0, const float* __restrict__ W1,
                     const float* __restrict__ W2, const float* __restrict__ W3,
                     const float* __restrict__ b0, const float* __restrict__ b1,
                     const float* __restrict__ b2, const float* __restrict__ b3,
                     float* __restrict__ Out)
{
    // gate order: 0=z, 1=g, 2=r, 3=h
    __shared__ __align__(16) unsigned short lWT[4][64][64]; // W transposed, bf16, XOR-swizzled (32 KB)
    __shared__ __align__(16) unsigned short lS[64][64];     // S tile bf16, swizzled (8 KB)
    __shared__ __align__(16) unsigned short lR[64][64];     // R tile bf16, swizzled (8 KB)
    __shared__ __align__(16) float4 lUB[4][64];             // (U0,U1,U2,b) per gate/col (4 KB)
    __shared__ __align__(16) float4 lX4[64];                // (x0,x1,x2,-) per row (1 KB)

    const int tid = threadIdx.x;

    // ---- one-time staging: weights -> LDS ----
    {
        const float* Ws[4] = {W0, W1, W2, W3};
        #pragma unroll
        for (int g = 0; g < 4; ++g) {
            const float* Wg = Ws[g];
            for (int idx = tid; idx < 4096; idx += 256) {   // coalesced: idx = k*64+n
                int k = idx >> 6, n = idx & 63;
                unsigned short h = f2b_rne(Wg[idx]);
                int byte = ((n << 7) + (k << 1)) ^ ((n & 7) << 4);
                *(unsigned short*)((char*)(&lWT[g][0][0]) + byte) = h;
            }
        }
        const float* Us[4] = {U0, U1, U2, U3};
        const float* bs[4] = {b0, b1, b2, b3};
        int g = tid >> 6, n = tid & 63;                     // exactly 256 entries
        lUB[g][n] = make_float4(Us[g][n], Us[g][64 + n], Us[g][128 + n], bs[g][n]);
    }

    const int w   = tid >> 6;      // wave id (0..3) -> rows w*16..w*16+15 of the tile
    const int l   = tid & 63;
    const int l15 = l & 15;
    const int lg  = l >> 4;        // k-group
    const int rbase = w << 4;

    for (int tile = blockIdx.x; tile < NTILES; tile += gridDim.x) {
        const int row0 = tile << 6;
        __syncthreads();  // protect lS/lR/lX4 from previous iteration's readers

        // ---- Phase A: stage S tile (f32 -> bf16, swizzled) + X ----
        {
            int r  = tid >> 2;
            int cb = (tid & 3) << 4;
            const float4* src = (const float4*)(S + (size_t)(row0 + r) * 64 + cb);
            float4 v0 = src[0], v1 = src[1], v2 = src[2], v3 = src[3];
            uint4 p0, p1;
            p0.x = (unsigned)f2b_rne(v0.x) | ((unsigned)f2b_rne(v0.y) << 16);
            p0.y = (unsigned)f2b_rne(v0.z) | ((unsigned)f2b_rne(v0.w) << 16);
            p0.z = (unsigned)f2b_rne(v1.x) | ((unsigned)f2b_rne(v1.y) << 16);
            p0.w = (unsigned)f2b_rne(v1.z) | ((unsigned)f2b_rne(v1.w) << 16);
            p1.x = (unsigned)f2b_rne(v2.x) | ((unsigned)f2b_rne(v2.y) << 16);
            p1.y = (unsigned)f2b_rne(v2.z) | ((unsigned)f2b_rne(v2.w) << 16);
            p1.z = (unsigned)f2b_rne(v3.x) | ((unsigned)f2b_rne(v3.y) << 16);
            p1.w = (unsigned)f2b_rne(v3.z) | ((unsigned)f2b_rne(v3.w) << 16);
            int base = (r << 7) + (cb << 1);
            int swz  = (r & 7) << 4;
            *(uint4*)((char*)(&lS[0][0]) + ( base        ^ swz)) = p0;
            *(uint4*)((char*)(&lS[0][0]) + ((base + 16)  ^ swz)) = p1;

            if (tid < 192) {
                float xv = X[(size_t)row0 * 3 + tid];
                ((float*)&lX4[0])[(tid / 3) * 4 + (tid % 3)] = xv;
            }
        }
        __syncthreads();

        // ---- Phase B: A-fragments of S, then Z/G/R matmuls + epilogues ----
        bf16x8 aS[2];
        #pragma unroll
        for (int ks = 0; ks < 2; ++ks) {
            int row  = rbase + l15;
            int byte = ((row << 7) + (ks << 6) + (lg << 4)) ^ ((row & 7) << 4);
            aS[ks] = *(const bf16x8*)((const char*)(&lS[0][0]) + byte);
        }
        float xr[4][3];
        #pragma unroll
        for (int m = 0; m < 4; ++m) {
            float4 x4 = lX4[rbase + (lg << 2) + m];
            xr[m][0] = x4.x; xr[m][1] = x4.y; xr[m][2] = x4.z;
        }

        float zv[4][4], gv[4][4];
        #pragma unroll
        for (int gate = 0; gate < 3; ++gate) {
            f32x4 acc[4] = {};
            #pragma unroll
            for (int ks = 0; ks < 2; ++ks) {
                #pragma unroll
                for (int nt = 0; nt < 4; ++nt) {
                    int n    = (nt << 4) + l15;
                    int byte = ((n << 7) + (ks << 6) + (lg << 4)) ^ ((n & 7) << 4);
                    bf16x8 bw = *(const bf16x8*)((const char*)(&lWT[gate][0][0]) + byte);
                    acc[nt] = __builtin_amdgcn_mfma_f32_16x16x32_bf16(aS[ks], bw, acc[nt], 0, 0, 0);
                }
            }
            #pragma unroll
            for (int nt = 0; nt < 4; ++nt) {
                float4 ub = lUB[gate][(nt << 4) + l15];
                #pragma unroll
                for (int m = 0; m < 4; ++m) {
                    float pre = acc[nt][m] + ub.w + xr[m][0] * ub.x + xr[m][1] * ub.y + xr[m][2] * ub.z;
                    float t = tanh_fast(pre);
                    if (gate == 0)      zv[nt][m] = t;
                    else if (gate == 1) gv[nt][m] = t;
                    else {
                        int rowm = rbase + (lg << 2) + m;
                        int n    = (nt << 4) + l15;
                        int byte = ((rowm << 7) + (n << 1)) ^ ((rowm & 7) << 4);
                        *(unsigned short*)((char*)(&lR[0][0]) + byte) = f2b_rne(t);
                    }
                }
            }
        }
        __syncthreads();  // lR visible (C-layout writes -> A-layout reads)

        // ---- Phase D: (S*R) @ Wh ----
        f32x4 accH[4] = {};
        #pragma unroll
        for (int ks = 0; ks < 2; ++ks) {
            int row  = rbase + l15;
            int byte = ((row << 7) + (ks << 6) + (lg << 4)) ^ ((row & 7) << 4);
            bf16x8 aR = *(const bf16x8*)((const char*)(&lR[0][0]) + byte);
            bf16x8 aSR;
            #pragma unroll
            for (int i = 0; i < 8; ++i) {
                float p = b2f((unsigned short)aS[ks][i]) * b2f((unsigned short)aR[i]);
                aSR[i] = (short)f2b_rne(p);
            }
            #pragma unroll
            for (int nt = 0; nt < 4; ++nt) {
                int n     = (nt << 4) + l15;
                int byte2 = ((n << 7) + (ks << 6) + (lg << 4)) ^ ((n & 7) << 4);
                bf16x8 bw = *(const bf16x8*)((const char*)(&lWT[3][0][0]) + byte2);
                accH[nt] = __builtin_amdgcn_mfma_f32_16x16x32_bf16(aSR, bw, accH[nt], 0, 0, 0);
            }
        }

        // ---- Phase E: H epilogue + final combine + store ----
        #pragma unroll
        for (int nt = 0; nt < 4; ++nt) {
            float4 ub = lUB[3][(nt << 4) + l15];
            #pragma unroll
            for (int m = 0; m < 4; ++m) {
                float pre = accH[nt][m] + ub.w + xr[m][0] * ub.x + xr[m][1] * ub.y + xr[m][2] * ub.z;
                float h = tanh_fast(pre);
                int rowm = rbase + (lg << 2) + m;
                int n    = (nt << 4) + l15;
                int byte = ((rowm << 7) + (n << 1)) ^ ((rowm & 7) << 4);
                float s  = b2f(*(const unsigned short*)((const char*)(&lS[0][0]) + byte));
                float out = (1.0f - gv[nt][m]) * h + zv[nt][m] * s;
                Out[(size_t)(row0 + rowm) * 64 + n] = out;
            }
        }
    }
}

extern "C" void kernel_launch(void* const* d_in, const int* in_sizes, int n_in,
                              void* d_out, int out_size, void* d_ws, size_t ws_size,
                              hipStream_t stream) {
    dim3 grid(2048), block(256);
    dgm_lstm_kernel<<<grid, block, 0, stream>>>(
        (const float*)d_in[0],  (const float*)d_in[1],
        (const float*)d_in[2],  (const float*)d_in[3],
        (const float*)d_in[4],  (const float*)d_in[5],
        (const float*)d_in[6],  (const float*)d_in[7],
        (const float*)d_in[8],  (const float*)d_in[9],
        (const float*)d_in[10], (const float*)d_in[11],
        (const float*)d_in[12], (const float*)d_in[13],
        (float*)d_out);
}

// Round 2
// 153.842 us; speedup vs baseline: 1.2382x; 1.2382x over previous
//
#include <hip/hip_runtime.h>

#define NTILES 15625   // 1,000,000 / 64

typedef __attribute__((ext_vector_type(8))) short bf16x8;
typedef __attribute__((ext_vector_type(4))) float f32x4;

__device__ __forceinline__ short f2b(float f) {
    __bf16 h = (__bf16)f;                 // hardware RNE: v_cvt_pk_bf16_f32
    return __builtin_bit_cast(short, h);
}
__device__ __forceinline__ float tanh_fast(float x) {
    float e = __expf(2.0f * x);
    return 1.0f - 2.0f * __builtin_amdgcn_rcpf(e + 1.0f);
}

template <int G>
__device__ __forceinline__ void gate_mm(const unsigned short (&lWT)[4][64][64],
                                        const bf16x8 (&baug)[4],
                                        bf16x8 aX, bf16x8 aS0, bf16x8 aS1,
                                        int l15, int lg, f32x4 (&acc)[4])
{
    const f32x4 z4 = {0.f, 0.f, 0.f, 0.f};
    #pragma unroll
    for (int nt = 0; nt < 4; ++nt)
        acc[nt] = __builtin_amdgcn_mfma_f32_16x16x32_bf16(aX, baug[nt], z4, 0, 0, 0);
    #pragma unroll
    for (int ks = 0; ks < 2; ++ks) {
        bf16x8 a = ks ? aS1 : aS0;
        #pragma unroll
        for (int nt = 0; nt < 4; ++nt) {
            int n   = (nt << 4) + l15;
            int byt = ((n << 7) + (ks << 6) + (lg << 4)) ^ ((n & 7) << 4);
            bf16x8 bw = *(const bf16x8*)((const char*)(&lWT[G][0][0]) + byt);
            acc[nt] = __builtin_amdgcn_mfma_f32_16x16x32_bf16(a, bw, acc[nt], 0, 0, 0);
        }
    }
}

__global__ __launch_bounds__(256, 2)
void dgm_lstm_kernel(const float* __restrict__ S, const float* __restrict__ X,
                     const float* __restrict__ U0, const float* __restrict__ U1,
                     const float* __restrict__ U2, const float* __restrict__ U3,
                     const float* __restrict__ W0, const float* __restrict__ W1,
                     const float* __restrict__ W2, const float* __restrict__ W3,
                     const float* __restrict__ b0, const float* __restrict__ b1,
                     const float* __restrict__ b2, const float* __restrict__ b3,
                     float* __restrict__ Out)
{
    // gate order: 0=z, 1=g, 2=r, 3=h
    __shared__ __align__(16) unsigned short lWT[4][64][64];   // 32 KB: W^T bf16, XOR-swizzled
    __shared__ __align__(16) unsigned short lR[2][64][64];    // 16 KB: (S*R) tile, double-buffered

    const int tid = threadIdx.x;
    const int l   = tid & 63;
    const int wv  = tid >> 6;
    const int l15 = l & 15;
    const int lg  = l >> 4;
    const int rbase = wv << 4;

    // ---- one-time: W -> LDS (bf16, transposed, swizzled) ----
    {
        const float* Ws[4] = {W0, W1, W2, W3};
        #pragma unroll
        for (int g = 0; g < 4; ++g) {
            const float* Wg = Ws[g];
            #pragma unroll
            for (int t = 0; t < 4; ++t) {
                int idx = (t * 256 + tid) * 4;               // idx = k*64 + n, 4 consecutive n
                float4 v = *(const float4*)(Wg + idx);
                int k = idx >> 6, n = idx & 63;
                #pragma unroll
                for (int j = 0; j < 4; ++j) {
                    int nn  = n + j;
                    int byt = ((nn << 7) + (k << 1)) ^ ((nn & 7) << 4);
                    *(unsigned short*)((char*)(&lWT[g][0][0]) + byt) =
                        (unsigned short)f2b(j == 0 ? v.x : j == 1 ? v.y : j == 2 ? v.z : v.w);
                }
            }
        }
    }

    // ---- one-time: B_aug fragments (tile-invariant, registers) ----
    bf16x8 Baug0[4], Baug1[4], Baug2[4], Baug3[4];
    {
        const float* Us[4] = {U0, U1, U2, U3};
        const float* bs[4] = {b0, b1, b2, b3};
        #pragma unroll
        for (int g = 0; g < 4; ++g) {
            #pragma unroll
            for (int nt = 0; nt < 4; ++nt) {
                int n = (nt << 4) + l15;
                float u0 = 0.f, u1 = 0.f, u2 = 0.f, bb = 0.f;
                if (lg == 0) {
                    u0 = Us[g][n]; u1 = Us[g][64 + n]; u2 = Us[g][128 + n]; bb = bs[g][n];
                }
                bf16x8 f = {};
                f[0] = f2b(u0); f[1] = f2b(u1); f[2] = f2b(u2); f[3] = f2b(bb);
                if (g == 0) Baug0[nt] = f;
                else if (g == 1) Baug1[nt] = f;
                else if (g == 2) Baug2[nt] = f;
                else Baug3[nt] = f;
            }
        }
    }

    __syncthreads();

    int parity = 0;
    for (int tile = blockIdx.x; tile < NTILES; tile += gridDim.x, parity ^= 1) {
        const int row0 = tile << 6;
        const int r15  = rbase + l15;

        // ---- A-fragments of S, straight from global (f32 -> bf16 in-register) ----
        const float* Sr = S + (size_t)(row0 + r15) * 64 + (lg << 3);
        float4 sa0 = *(const float4*)(Sr);
        float4 sa1 = *(const float4*)(Sr + 4);
        float4 sb0 = *(const float4*)(Sr + 32);
        float4 sb1 = *(const float4*)(Sr + 36);
        bf16x8 aS0, aS1;
        aS0[0] = f2b(sa0.x); aS0[1] = f2b(sa0.y); aS0[2] = f2b(sa0.z); aS0[3] = f2b(sa0.w);
        aS0[4] = f2b(sa1.x); aS0[5] = f2b(sa1.y); aS0[6] = f2b(sa1.z); aS0[7] = f2b(sa1.w);
        aS1[0] = f2b(sb0.x); aS1[1] = f2b(sb0.y); aS1[2] = f2b(sb0.z); aS1[3] = f2b(sb0.w);
        aS1[4] = f2b(sb1.x); aS1[5] = f2b(sb1.y); aS1[6] = f2b(sb1.z); aS1[7] = f2b(sb1.w);

        // ---- A_aug = [x0,x1,x2,1,0,...] on lg==0 lanes ----
        float x0 = 0.f, x1 = 0.f, x2 = 0.f, x3 = 0.f;
        if (lg == 0) {
            const float* Xr = X + (size_t)(row0 + r15) * 3;
            x0 = Xr[0]; x1 = Xr[1]; x2 = Xr[2]; x3 = 1.0f;
        }
        bf16x8 aX = {};
        aX[0] = f2b(x0); aX[1] = f2b(x1); aX[2] = f2b(x2); aX[3] = f2b(x3);

        // ---- S values in C-layout (f32, L2-hot re-read) ----
        float sv[4][4];
        #pragma unroll
        for (int m = 0; m < 4; ++m) {
            int rowm = rbase + (lg << 2) + m;
            const float* Sc = S + (size_t)(row0 + rowm) * 64 + l15;
            #pragma unroll
            for (int nt = 0; nt < 4; ++nt)
                sv[nt][m] = Sc[nt << 4];
        }

        // ---- gates Z, G ----
        f32x4 acc[4];
        float zv[4][4], gq[4][4];
        gate_mm<0>(lWT, Baug0, aX, aS0, aS1, l15, lg, acc);
        #pragma unroll
        for (int nt = 0; nt < 4; ++nt)
            #pragma unroll
            for (int m = 0; m < 4; ++m)
                zv[nt][m] = tanh_fast(acc[nt][m]);

        gate_mm<1>(lWT, Baug1, aX, aS0, aS1, l15, lg, acc);
        #pragma unroll
        for (int nt = 0; nt < 4; ++nt)
            #pragma unroll
            for (int m = 0; m < 4; ++m)
                gq[nt][m] = 1.0f - tanh_fast(acc[nt][m]);

        // ---- gate R: write s*r (bf16, swizzled) into double-buffered lR ----
        gate_mm<2>(lWT, Baug2, aX, aS0, aS1, l15, lg, acc);
        char* lRb = (char*)(&lR[parity][0][0]);
        #pragma unroll
        for (int nt = 0; nt < 4; ++nt) {
            int n = (nt << 4) + l15;
            #pragma unroll
            for (int m = 0; m < 4; ++m) {
                float t  = tanh_fast(acc[nt][m]);
                float sr = sv[nt][m] * t;
                int rowm = rbase + (lg << 2) + m;
                int byt  = ((rowm << 7) + (n << 1)) ^ ((rowm & 7) << 4);
                *(unsigned short*)(lRb + byt) = (unsigned short)f2b(sr);
            }
        }
        __syncthreads();

        // ---- gate H: (S*R) @ Wh + X@Uh + bh ----
        const f32x4 z4 = {0.f, 0.f, 0.f, 0.f};
        f32x4 accH[4];
        #pragma unroll
        for (int nt = 0; nt < 4; ++nt)
            accH[nt] = __builtin_amdgcn_mfma_f32_16x16x32_bf16(aX, Baug3[nt], z4, 0, 0, 0);
        {
            int row = rbase + l15;
            int by0 = ((row << 7) + (0 << 6) + (lg << 4)) ^ ((row & 7) << 4);
            int by1 = ((row << 7) + (1 << 6) + (lg << 4)) ^ ((row & 7) << 4);
            bf16x8 aR0 = *(const bf16x8*)(lRb + by0);
            bf16x8 aR1 = *(const bf16x8*)(lRb + by1);
            #pragma unroll
            for (int ks = 0; ks < 2; ++ks) {
                bf16x8 a = ks ? aR1 : aR0;
                #pragma unroll
                for (int nt = 0; nt < 4; ++nt) {
                    int n   = (nt << 4) + l15;
                    int byt = ((n << 7) + (ks << 6) + (lg << 4)) ^ ((n & 7) << 4);
                    bf16x8 bw = *(const bf16x8*)((const char*)(&lWT[3][0][0]) + byt);
                    accH[nt] = __builtin_amdgcn_mfma_f32_16x16x32_bf16(a, bw, accH[nt], 0, 0, 0);
                }
            }
        }

        // ---- final combine + nontemporal store ----
        #pragma unroll
        for (int nt = 0; nt < 4; ++nt) {
            int n = (nt << 4) + l15;
            #pragma unroll
            for (int m = 0; m < 4; ++m) {
                float h   = tanh_fast(accH[nt][m]);
                int rowm  = rbase + (lg << 2) + m;
                float out = fmaf(zv[nt][m], sv[nt][m], gq[nt][m] * h);
                __builtin_nontemporal_store(out, Out + (size_t)(row0 + rowm) * 64 + n);
            }
        }
    }
}

extern "C" void kernel_launch(void* const* d_in, const int* in_sizes, int n_in,
                              void* d_out, int out_size, void* d_ws, size_t ws_size,
                              hipStream_t stream) {
    dim3 grid(2048), block(256);
    dgm_lstm_kernel<<<grid, block, 0, stream>>>(
        (const float*)d_in[0],  (const float*)d_in[1],
        (const float*)d_in[2],  (const float*)d_in[3],
        (const float*)d_in[4],  (const float*)d_in[5],
        (const float*)d_in[6],  (const float*)d_in[7],
        (const float*)d_in[8],  (const float*)d_in[9],
        (const float*)d_in[10], (const float*)d_in[11],
        (const float*)d_in[12], (const float*)d_in[13],
        (float*)d_out);
}

// Round 3
// 151.543 us; speedup vs baseline: 1.2570x; 1.0152x over previous
//
#include <hip/hip_runtime.h>

#define NTILES 15625   // 1,000,000 / 64
#define GRID   3125    // 5 tiles per block, uniform

typedef __attribute__((ext_vector_type(8))) short bf16x8;
typedef __attribute__((ext_vector_type(4))) float f32x4;

__device__ __forceinline__ short f2b(float f) {
    __bf16 h = (__bf16)f;                 // hardware RNE (v_cvt_pk_bf16_f32 when paired)
    return __builtin_bit_cast(short, h);
}
__device__ __forceinline__ float tanh_fast(float x) {
    float e = __expf(2.0f * x);
    return 1.0f - 2.0f * __builtin_amdgcn_rcpf(e + 1.0f);
}

// One gate: acc = Xaug @ Baug + S @ W   (all 16x16x32 MFMAs)
__device__ __forceinline__ void gate_mm(const char* lWg, const char* lBg,
                                        const int (&baOff)[4], const int (&wOff)[2][4],
                                        bf16x8 aX, bf16x8 aS0, bf16x8 aS1,
                                        f32x4 (&acc)[4])
{
    #pragma unroll
    for (int nt = 0; nt < 4; ++nt) {
        bf16x8 bx = *(const bf16x8*)(lBg + baOff[nt]);
        f32x4 z4 = {0.f, 0.f, 0.f, 0.f};
        acc[nt] = __builtin_amdgcn_mfma_f32_16x16x32_bf16(aX, bx, z4, 0, 0, 0);
    }
    #pragma unroll
    for (int ks = 0; ks < 2; ++ks) {
        bf16x8 a = ks ? aS1 : aS0;
        #pragma unroll
        for (int nt = 0; nt < 4; ++nt) {
            bf16x8 bw = *(const bf16x8*)(lWg + wOff[ks][nt]);
            acc[nt] = __builtin_amdgcn_mfma_f32_16x16x32_bf16(a, bw, acc[nt], 0, 0, 0);
        }
    }
}

__global__ __launch_bounds__(256, 3)
void dgm_lstm_kernel(const float* __restrict__ S, const float* __restrict__ X,
                     const float* __restrict__ U0, const float* __restrict__ U1,
                     const float* __restrict__ U2, const float* __restrict__ U3,
                     const float* __restrict__ W0, const float* __restrict__ W1,
                     const float* __restrict__ W2, const float* __restrict__ W3,
                     const float* __restrict__ b0, const float* __restrict__ b1,
                     const float* __restrict__ b2, const float* __restrict__ b3,
                     float* __restrict__ Out)
{
    // gate order: 0=z, 1=g, 2=r, 3=h
    __shared__ __align__(16) unsigned short lWT[4][64][64]; // 32 KB: W^T bf16, XOR-swizzled
    __shared__ __align__(16) unsigned short lBa[4][66][8];  // 4.1 KB: [U0,U1,U2,b,0..] per n; row 64 = zeros
    __shared__ __align__(16) unsigned short lR[64][64];     // 8 KB: (S*R), intra-wave only

    const int tid = threadIdx.x;

    // ---- one-time staging ----
    {
        const float* Ws[4] = {W0, W1, W2, W3};
        #pragma unroll
        for (int g = 0; g < 4; ++g) {
            const float* Wg = Ws[g];
            #pragma unroll
            for (int t = 0; t < 4; ++t) {
                int idx = (t * 256 + tid) * 4;              // idx = k*64 + n
                float4 v = *(const float4*)(Wg + idx);
                int k = idx >> 6, n = idx & 63;
                #pragma unroll
                for (int j = 0; j < 4; ++j) {
                    int nn  = n + j;
                    int byt = ((nn << 7) + (k << 1)) ^ ((nn & 7) << 4);
                    *(unsigned short*)((char*)(&lWT[0][0][0]) + (g << 13) + byt) =
                        (unsigned short)f2b(j == 0 ? v.x : j == 1 ? v.y : j == 2 ? v.z : v.w);
                }
            }
        }
        const float* Us[4] = {U0, U1, U2, U3};
        const float* bs[4] = {b0, b1, b2, b3};
        int g = tid >> 6, n = tid & 63;
        bf16x8 f = {};
        f[0] = f2b(Us[g][n]); f[1] = f2b(Us[g][64 + n]);
        f[2] = f2b(Us[g][128 + n]); f[3] = f2b(bs[g][n]);
        *(bf16x8*)(&lBa[g][n][0]) = f;
        if (tid < 8) { bf16x8 z = {}; *(bf16x8*)(&lBa[tid >> 1][64 + (tid & 1)][0]) = z; }
    }
    __syncthreads();

    const int l   = tid & 63;
    const int wv  = tid >> 6;
    const int l15 = l & 15;
    const int lg  = l >> 4;
    const int rbase = wv << 4;

    char* lRb = (char*)&lR[0][0];
    const char* lWb = (const char*)&lWT[0][0];
    const char* lBb = (const char*)&lBa[0][0];

    // tile-invariant LDS byte offsets
    int baOff[4];
    #pragma unroll
    for (int nt = 0; nt < 4; ++nt)
        baOff[nt] = ((lg == 0) ? (l15 + (nt << 4)) : 64) << 4;
    int wOff[2][4];
    #pragma unroll
    for (int ks = 0; ks < 2; ++ks)
        #pragma unroll
        for (int nt = 0; nt < 4; ++nt) {
            int n = l15 + (nt << 4);
            wOff[ks][nt] = ((n << 7) + (ks << 6) + (lg << 4)) ^ ((n & 7) << 4);
        }
    int rdOff[2];
    #pragma unroll
    for (int ks = 0; ks < 2; ++ks) {
        int row = rbase + l15;
        rdOff[ks] = ((row << 7) + (ks << 6) + (lg << 4)) ^ ((row & 7) << 4);
    }

    // ---- prologue prefetch (tile = blockIdx.x) ----
    int tile = blockIdx.x;
    float4 nsa0, nsa1, nsa2, nsa3;
    float nx0 = 0.f, nx1 = 0.f, nx2 = 0.f;
    {
        const float* Sr = S + (size_t)((tile << 6) + rbase + l15) * 64 + (lg << 3);
        nsa0 = *(const float4*)(Sr);      nsa1 = *(const float4*)(Sr + 4);
        nsa2 = *(const float4*)(Sr + 32); nsa3 = *(const float4*)(Sr + 36);
        if (lg == 0) {
            const float* Xr = X + (size_t)((tile << 6) + rbase + l15) * 3;
            nx0 = Xr[0]; nx1 = Xr[1]; nx2 = Xr[2];
        }
    }

    const short one_bf = (short)0x3F80;   // bf16(1.0)

    for (; tile < NTILES; tile += GRID) {
        const int row0 = tile << 6;
        float4 sa0 = nsa0, sa1 = nsa1, sa2 = nsa2, sa3 = nsa3;
        float x0 = nx0, x1 = nx1, x2 = nx2;

        // ---- issue next tile's loads (latency hidden under this tile's compute) ----
        int tn = tile + GRID;
        if (tn < NTILES) {
            const float* Sr = S + (size_t)((tn << 6) + rbase + l15) * 64 + (lg << 3);
            nsa0 = *(const float4*)(Sr);      nsa1 = *(const float4*)(Sr + 4);
            nsa2 = *(const float4*)(Sr + 32); nsa3 = *(const float4*)(Sr + 36);
            if (lg == 0) {
                const float* Xr = X + (size_t)((tn << 6) + rbase + l15) * 3;
                nx0 = Xr[0]; nx1 = Xr[1]; nx2 = Xr[2];
            }
        }

        // ---- C-layout S loads (L1/L2-hot: same lines as last iter's prefetch) ----
        float sv[4][4];
        #pragma unroll
        for (int m = 0; m < 4; ++m) {
            const float* Sc = S + (size_t)(row0 + rbase + (lg << 2) + m) * 64 + l15;
            #pragma unroll
            for (int nt = 0; nt < 4; ++nt) sv[nt][m] = Sc[nt << 4];
        }

        // ---- build fragments ----
        bf16x8 aS0, aS1, aX = {};
        aS0[0] = f2b(sa0.x); aS0[1] = f2b(sa0.y); aS0[2] = f2b(sa0.z); aS0[3] = f2b(sa0.w);
        aS0[4] = f2b(sa1.x); aS0[5] = f2b(sa1.y); aS0[6] = f2b(sa1.z); aS0[7] = f2b(sa1.w);
        aS1[0] = f2b(sa2.x); aS1[1] = f2b(sa2.y); aS1[2] = f2b(sa2.z); aS1[3] = f2b(sa2.w);
        aS1[4] = f2b(sa3.x); aS1[5] = f2b(sa3.y); aS1[6] = f2b(sa3.z); aS1[7] = f2b(sa3.w);
        aX[0] = f2b(x0); aX[1] = f2b(x1); aX[2] = f2b(x2);
        aX[3] = (lg == 0) ? one_bf : (short)0;

        f32x4 acc[4];

        // ---- gate R first: write s*r into lR (intra-wave rows only) ----
        gate_mm(lWb + (2 << 13), lBb + 2 * 1056, baOff, wOff, aX, aS0, aS1, acc);
        #pragma unroll
        for (int nt = 0; nt < 4; ++nt) {
            int n = l15 + (nt << 4);
            #pragma unroll
            for (int m = 0; m < 4; ++m) {
                float t  = tanh_fast(acc[nt][m]);
                float sr = sv[nt][m] * t;
                int rowm = rbase + (lg << 2) + m;
                int byt  = ((rowm << 7) + (n << 1)) ^ ((rowm & 7) << 4);
                *(unsigned short*)(lRb + byt) = (unsigned short)f2b(sr);
            }
        }

        // ---- gates Z, G (lR ds_writes drain underneath) ----
        float zv[4][4], gq[4][4];
        gate_mm(lWb + (0 << 13), lBb + 0 * 1056, baOff, wOff, aX, aS0, aS1, acc);
        #pragma unroll
        for (int nt = 0; nt < 4; ++nt)
            #pragma unroll
            for (int m = 0; m < 4; ++m)
                zv[nt][m] = tanh_fast(acc[nt][m]);

        gate_mm(lWb + (1 << 13), lBb + 1 * 1056, baOff, wOff, aX, aS0, aS1, acc);
        #pragma unroll
        for (int nt = 0; nt < 4; ++nt)
            #pragma unroll
            for (int m = 0; m < 4; ++m)
                gq[nt][m] = 1.0f - tanh_fast(acc[nt][m]);

        // ---- intra-wave LDS fence (no barrier needed: rows are wave-private) ----
        asm volatile("s_waitcnt lgkmcnt(0)" ::: "memory");
        __builtin_amdgcn_sched_barrier(0);

        // ---- gate H: (S*R) @ Wh + X@Uh + bh ----
        bf16x8 aR0 = *(const bf16x8*)(lRb + rdOff[0]);
        bf16x8 aR1 = *(const bf16x8*)(lRb + rdOff[1]);
        gate_mm(lWb + (3 << 13), lBb + 3 * 1056, baOff, wOff, aX, aR0, aR1, acc);

        // ---- epilogue: combine + store ----
        float* Or = Out + (size_t)row0 * 64;
        #pragma unroll
        for (int nt = 0; nt < 4; ++nt) {
            int n = l15 + (nt << 4);
            #pragma unroll
            for (int m = 0; m < 4; ++m) {
                float h   = tanh_fast(acc[nt][m]);
                int rowm  = rbase + (lg << 2) + m;
                Or[(size_t)rowm * 64 + n] = fmaf(zv[nt][m], sv[nt][m], gq[nt][m] * h);
            }
        }
    }
}

extern "C" void kernel_launch(void* const* d_in, const int* in_sizes, int n_in,
                              void* d_out, int out_size, void* d_ws, size_t ws_size,
                              hipStream_t stream) {
    dim3 grid(GRID), block(256);
    dgm_lstm_kernel<<<grid, block, 0, stream>>>(
        (const float*)d_in[0],  (const float*)d_in[1],
        (const float*)d_in[2],  (const float*)d_in[3],
        (const float*)d_in[4],  (const float*)d_in[5],
        (const float*)d_in[6],  (const float*)d_in[7],
        (const float*)d_in[8],  (const float*)d_in[9],
        (const float*)d_in[10], (const float*)d_in[11],
        (const float*)d_in[12], (const float*)d_in[13],
        (float*)d_out);
}